// Round 1
// baseline (180.253 us; speedup 1.0000x reference)
//
#include <hip/hip_runtime.h>
#include <stdint.h>

// Problem constants (CLUSTER_AMNT=1024, CLUSTER_SIZE=8, EMBED_DIM=128)
#define N_TOTAL 8192
#define EMBED   128
#define CSIZE   8
#define MARGIN  1.0f

typedef __attribute__((ext_vector_type(8))) short  short8;   // 8 bf16 (4 VGPRs)
typedef __attribute__((ext_vector_type(4))) float  floatx4;  // MFMA C/D

__device__ __forceinline__ unsigned short f2bf(float f) {
    union { float f; unsigned u; } v; v.f = f;
    unsigned u = v.u;
    // round-to-nearest-even bf16
    unsigned r = u + 0x7FFFu + ((u >> 16) & 1u);
    return (unsigned short)(r >> 16);
}

// ---------------------------------------------------------------------------
// prep: fp32 -> bf16 copy, squared row norms (fp32, exact), init negBits=+inf
// 4 threads per row; thread q handles k in [q*32, q*32+32)
// ---------------------------------------------------------------------------
__global__ void prep_kernel(const float* __restrict__ emb,
                            unsigned short* __restrict__ ebf,
                            float* __restrict__ n2,
                            unsigned* __restrict__ negBits) {
    int t   = blockIdx.x * blockDim.x + threadIdx.x;   // 32768 threads
    int row = t >> 2;
    int q   = t & 3;
    const float4* src = (const float4*)(emb + row * EMBED + q * 32);
    ushort4*      dst = (ushort4*)(ebf + row * EMBED + q * 32);
    float s = 0.f;
#pragma unroll
    for (int i = 0; i < 8; ++i) {
        float4 v = src[i];
        s += v.x * v.x + v.y * v.y + v.z * v.z + v.w * v.w;
        ushort4 o;
        o.x = f2bf(v.x); o.y = f2bf(v.y); o.z = f2bf(v.z); o.w = f2bf(v.w);
        dst[i] = o;
    }
    s += __shfl_xor(s, 1);
    s += __shfl_xor(s, 2);
    if (q == 0) {
        n2[row]      = s;
        negBits[row] = 0x7F800000u;  // +inf
    }
}

// ---------------------------------------------------------------------------
// pos: hard positive per row, exact fp32 norms inside each 8-element cluster.
// One wave per cluster; thread t = pair (i = t>>3, j = t&7).
// ---------------------------------------------------------------------------
__global__ void pos_kernel(const float* __restrict__ emb,
                           float* __restrict__ ap) {
    __shared__ float ls[CSIZE][EMBED + 4];  // +4 pad -> rows land on distinct banks
    int c = blockIdx.x;
    int t = threadIdx.x;  // 0..63
    const float4* base = (const float4*)(emb + c * CSIZE * EMBED);
#pragma unroll
    for (int i = 0; i < 4; ++i) {
        int idx4 = t + i * 64;            // 256 float4 total
        float4 v = base[idx4];
        int idx = idx4 * 4;
        int r = idx >> 7, k = idx & 127;
        ls[r][k] = v.x; ls[r][k + 1] = v.y; ls[r][k + 2] = v.z; ls[r][k + 3] = v.w;
    }
    __syncthreads();
    int i = t >> 3, j = t & 7;
    float sq = 0.f;
#pragma unroll 4
    for (int k = 0; k < EMBED; k += 4) {
        float d0 = ls[i][k]     - ls[j][k];
        float d1 = ls[i][k + 1] - ls[j][k + 1];
        float d2 = ls[i][k + 2] - ls[j][k + 2];
        float d3 = ls[i][k + 3] - ls[j][k + 3];
        sq += d0 * d0 + d1 * d1 + d2 * d2 + d3 * d3;
    }
    // max over j within the 8-lane group (lane bits 0..2)
#pragma unroll
    for (int off = 1; off < 8; off <<= 1) sq = fmaxf(sq, __shfl_xor(sq, off));
    if (j == 0) ap[c * CSIZE + i] = sqrtf(sq);
}

// ---------------------------------------------------------------------------
// neg: min squared distance to any different-label point.
// bf16 MFMA Gram, 16x16 C-tiles. Block = 4 waves = 64 rows; grid =
// 128 rowBlocks x 8 column segments. Each wave owns a 16-row strip and
// iterates 64 column tiles (1024 columns), keeping 4 running mins per lane.
// ---------------------------------------------------------------------------
__global__ __launch_bounds__(256) void neg_kernel(
        const unsigned short* __restrict__ ebf,
        const float* __restrict__ n2,
        unsigned* __restrict__ negBits) {
    int lane = threadIdx.x & 63;
    int w    = threadIdx.x >> 6;
    int quad = lane >> 4;
    int l16  = lane & 15;
    int rowBlock = blockIdx.x >> 3;
    int seg      = blockIdx.x & 7;
    int rowStrip = rowBlock * 64 + w * 16;

    // A fragments for all K=128: A[m = l16][k = quad*8 + j + 32*c]
    short8 afrag[4];
#pragma unroll
    for (int c = 0; c < 4; ++c)
        afrag[c] = *(const short8*)(ebf + (size_t)(rowStrip + l16) * EMBED + c * 32 + quad * 8);

    // this lane's 4 output rows: rowStrip + quad*4 + r
    float n2r[4];
#pragma unroll
    for (int r = 0; r < 4; ++r) n2r[r] = n2[rowStrip + quad * 4 + r];

    float mn[4] = {3.0e38f, 3.0e38f, 3.0e38f, 3.0e38f};

    int colBase0 = seg * 1024;
    for (int ct = 0; ct < 64; ++ct) {
        int colBase = colBase0 + ct * 16;
        short8 bfrag[4];
#pragma unroll
        for (int c = 0; c < 4; ++c)
            bfrag[c] = *(const short8*)(ebf + (size_t)(colBase + l16) * EMBED + c * 32 + quad * 8);
        float n2c = n2[colBase + l16];

        floatx4 acc = {0.f, 0.f, 0.f, 0.f};
#pragma unroll
        for (int c = 0; c < 4; ++c)
            acc = __builtin_amdgcn_mfma_f32_16x16x32_bf16(afrag[c], bfrag[c], acc, 0, 0, 0);

        // same-label pairs occur only on diagonal tiles (16-aligned vs 8-sized
        // labels); there the lane's 4 rows share label-block quad>>1.
        bool skip = (colBase == rowStrip) && ((quad >> 1) == (l16 >> 3));
#pragma unroll
        for (int r = 0; r < 4; ++r) {
            float sq = fmaf(-2.f, acc[r], n2r[r] + n2c);  // n2_i + n2_j - 2*gram
            sq = skip ? 3.0e38f : sq;
            mn[r] = fminf(mn[r], sq);
        }
    }

    // reduce over the 16 columns held by lanes sharing this quad
#pragma unroll
    for (int r = 0; r < 4; ++r) {
#pragma unroll
        for (int off = 1; off < 16; off <<= 1)
            mn[r] = fminf(mn[r], __shfl_xor(mn[r], off));
    }
    if (l16 == 0) {
#pragma unroll
        for (int r = 0; r < 4; ++r)
            atomicMin(&negBits[rowStrip + quad * 4 + r],
                      __float_as_uint(fmaxf(mn[r], 0.f)));
    }
}

// ---------------------------------------------------------------------------
// finalize: loss_i = relu(ap_i - sqrt(negSq_i) + margin); mean via atomicAdd
// ---------------------------------------------------------------------------
__global__ void fin_kernel(const float* __restrict__ ap,
                           const unsigned* __restrict__ negBits,
                           float* __restrict__ out) {
    int i = blockIdx.x * blockDim.x + threadIdx.x;  // 8192 threads
    float an   = sqrtf(__uint_as_float(negBits[i]));
    float loss = fmaxf(ap[i] - an + MARGIN, 0.f);
#pragma unroll
    for (int off = 1; off < 64; off <<= 1) loss += __shfl_xor(loss, off);
    __shared__ float wsum[4];
    int lane = threadIdx.x & 63, wv = threadIdx.x >> 6;
    if (lane == 0) wsum[wv] = loss;
    __syncthreads();
    if (threadIdx.x == 0) {
        float s = wsum[0] + wsum[1] + wsum[2] + wsum[3];
        atomicAdd(out, s * (1.0f / N_TOTAL));
    }
}

extern "C" void kernel_launch(void* const* d_in, const int* in_sizes, int n_in,
                              void* d_out, int out_size, void* d_ws, size_t ws_size,
                              hipStream_t stream) {
    const float* emb = (const float*)d_in[0];
    float* out = (float*)d_out;

    char* ws = (char*)d_ws;
    unsigned short* ebf     = (unsigned short*)ws;                         // 2 MiB bf16 copy
    float*          n2      = (float*)(ws + 2 * 1024 * 1024);              // 32 KiB
    float*          ap      = (float*)(ws + 2 * 1024 * 1024 + 32 * 1024);  // 32 KiB
    unsigned*       negBits = (unsigned*)(ws + 2 * 1024 * 1024 + 64 * 1024);

    hipMemsetAsync(d_out, 0, sizeof(float), stream);
    prep_kernel<<<N_TOTAL * 4 / 256, 256, 0, stream>>>(emb, ebf, n2, negBits);
    pos_kernel <<<N_TOTAL / CSIZE, 64, 0, stream>>>(emb, ap);
    neg_kernel <<<(N_TOTAL / 64) * 8, 256, 0, stream>>>(ebf, n2, negBits);
    fin_kernel <<<N_TOTAL / 256, 256, 0, stream>>>(ap, negBits, out);
}

// Round 2
// 113.859 us; speedup vs baseline: 1.5831x; 1.5831x over previous
//
#include <hip/hip_runtime.h>
#include <stdint.h>

// Problem constants (CLUSTER_AMNT=1024, CLUSTER_SIZE=8, EMBED_DIM=128)
#define N_TOTAL 8192
#define EMBED   128
#define CSIZE   8
#define MARGIN  1.0f
#define BIGF    3.0e38f

typedef __attribute__((ext_vector_type(8))) short  short8;   // 8 bf16 (4 VGPRs)
typedef __attribute__((ext_vector_type(4))) float  floatx4;  // MFMA C/D

__device__ __forceinline__ unsigned short f2bf(float f) {
    union { float f; unsigned u; } v; v.f = f;
    unsigned u = v.u;
    unsigned r = u + 0x7FFFu + ((u >> 16) & 1u);  // RNE bf16
    return (unsigned short)(r >> 16);
}

// ---------------------------------------------------------------------------
// prep_pos: fused. 256 threads = 4 waves, one cluster per wave (wave-
// synchronous, no barriers). Per cluster: fp32->bf16 cast-out, exact fp32
// row norms, hard-positive distance (max within 8-cluster), negBits=+inf.
// Also zeroes the neg done-counter.
// ---------------------------------------------------------------------------
__global__ __launch_bounds__(256) void prep_pos_kernel(
        const float* __restrict__ emb,
        unsigned short* __restrict__ ebf,
        float* __restrict__ n2,
        float* __restrict__ ap,
        unsigned* __restrict__ negBits,
        unsigned* __restrict__ cnt) {
    __shared__ float ls[4][CSIZE][EMBED + 1];  // stride 129 -> conflict-free
    int tid  = threadIdx.x;
    int w    = tid >> 6;
    int lane = tid & 63;
    int c    = blockIdx.x * 4 + w;

    const float4* base = (const float4*)(emb + (size_t)c * CSIZE * EMBED);
    float4 v[4];
#pragma unroll
    for (int i = 0; i < 4; ++i) v[i] = base[lane + i * 64];

    // stash fp32 into LDS (row-major, padded)
#pragma unroll
    for (int i = 0; i < 4; ++i) {
        int elem = (lane + i * 64) * 4;
        int r = elem >> 7, k = elem & 127;
        ls[w][r][k]     = v[i].x;
        ls[w][r][k + 1] = v[i].y;
        ls[w][r][k + 2] = v[i].z;
        ls[w][r][k + 3] = v[i].w;
    }

    // bf16 cast-out (coalesced ushort4 stores)
    ushort4* dst = (ushort4*)(ebf + (size_t)c * CSIZE * EMBED);
#pragma unroll
    for (int i = 0; i < 4; ++i) {
        ushort4 o;
        o.x = f2bf(v[i].x); o.y = f2bf(v[i].y);
        o.z = f2bf(v[i].z); o.w = f2bf(v[i].w);
        dst[lane + i * 64] = o;
    }

    // pairwise: thread = (i8, j8); also exact row norm of row i8
    int i8 = lane >> 3, j8 = lane & 7;
    float sq = 0.f, s2 = 0.f;
#pragma unroll 8
    for (int k = 0; k < EMBED; ++k) {
        float a = ls[w][i8][k];
        float d = a - ls[w][j8][k];
        sq = fmaf(d, d, sq);
        s2 = fmaf(a, a, s2);
    }
#pragma unroll
    for (int off = 1; off < 8; off <<= 1) sq = fmaxf(sq, __shfl_xor(sq, off));
    if (j8 == 0) {
        ap[c * CSIZE + i8] = sqrtf(sq);
        n2[c * CSIZE + i8] = s2;
    }
    if (lane < CSIZE) negBits[c * CSIZE + lane] = 0x7F800000u;  // +inf
    if (blockIdx.x == 0 && tid == 0) cnt[0] = 0u;
}

// ---------------------------------------------------------------------------
// neg: min squared distance to any different-label point, bf16 MFMA Gram.
// Wave owns 64 rows (4 row-tiles x 16) held as register A-fragments; block =
// 4 waves = 256 rows. Grid = 32 rowBlocks x 16 column segments (512 cols).
// Per column tile: 4 double-buffered B loads feed 16 MFMAs (4 indep chains).
// Last block to finish reduces the loss and writes out[0].
// ---------------------------------------------------------------------------
__global__ __launch_bounds__(256, 2) void neg_kernel(
        const unsigned short* __restrict__ ebf,
        const float* __restrict__ n2,
        const float* __restrict__ ap,
        unsigned* __restrict__ negBits,
        unsigned* __restrict__ cnt,
        float* __restrict__ out) {
    int lane = threadIdx.x & 63;
    int w    = threadIdx.x >> 6;
    int quad = lane >> 4;
    int l16  = lane & 15;
    int rowBlock = blockIdx.x >> 4;     // 32
    int seg      = blockIdx.x & 15;     // 16 segments x 512 cols
    int rowStrip = rowBlock * 256 + w * 64;

    // A fragments: 4 row-tiles x 4 K-chunks. A[m=l16][k=quad*8+j+32c]
    short8 afrag[4][4];
#pragma unroll
    for (int rt = 0; rt < 4; ++rt)
#pragma unroll
        for (int c = 0; c < 4; ++c)
            afrag[rt][c] = *(const short8*)(ebf +
                (size_t)(rowStrip + rt * 16 + l16) * EMBED + c * 32 + quad * 8);

    float mn[4][4];
#pragma unroll
    for (int rt = 0; rt < 4; ++rt)
#pragma unroll
        for (int r = 0; r < 4; ++r) mn[rt][r] = BIGF;

    int colBase0 = seg * 512;
    bool skipLane = false;  // recomputed per diagonal tile

    // prime double buffer
    short8 bcur[4];
#pragma unroll
    for (int c = 0; c < 4; ++c)
        bcur[c] = *(const short8*)(ebf +
            (size_t)(colBase0 + l16) * EMBED + c * 32 + quad * 8);
    float n2c = n2[colBase0 + l16];

    for (int ct = 0; ct < 32; ++ct) {
        int colBase = colBase0 + ct * 16;
        int nxt = colBase0 + ((ct == 31) ? ct : ct + 1) * 16;  // clamp: stay in-bounds
        short8 bnxt[4];
#pragma unroll
        for (int c = 0; c < 4; ++c)
            bnxt[c] = *(const short8*)(ebf +
                (size_t)(nxt + l16) * EMBED + c * 32 + quad * 8);
        float n2cn = n2[nxt + l16];

        floatx4 acc[4] = {{0.f,0.f,0.f,0.f},{0.f,0.f,0.f,0.f},
                          {0.f,0.f,0.f,0.f},{0.f,0.f,0.f,0.f}};
#pragma unroll
        for (int c = 0; c < 4; ++c)
#pragma unroll
            for (int rt = 0; rt < 4; ++rt)
                acc[rt] = __builtin_amdgcn_mfma_f32_16x16x32_bf16(
                    afrag[rt][c], bcur[c], acc[rt], 0, 0, 0);

        // track min over j of (n2_j - 2*G_ij); n2_i added at the end.
#pragma unroll
        for (int rt = 0; rt < 4; ++rt) {
            if (colBase == rowStrip + rt * 16) {   // wave-uniform: diagonal tile
                bool skip = ((quad >> 1) == (l16 >> 3));  // same 8-cluster
#pragma unroll
                for (int r = 0; r < 4; ++r) {
                    float sq = fmaf(-2.f, acc[rt][r], n2c);
                    sq = skip ? BIGF : sq;
                    mn[rt][r] = fminf(mn[rt][r], sq);
                }
            } else {
#pragma unroll
                for (int r = 0; r < 4; ++r) {
                    float sq = fmaf(-2.f, acc[rt][r], n2c);
                    mn[rt][r] = fminf(mn[rt][r], sq);
                }
            }
        }
#pragma unroll
        for (int c = 0; c < 4; ++c) bcur[c] = bnxt[c];
        n2c = n2cn;
    }

    // reduce over the 16 columns held by lanes sharing this quad, then commit
#pragma unroll
    for (int rt = 0; rt < 4; ++rt) {
#pragma unroll
        for (int r = 0; r < 4; ++r) {
            float m = mn[rt][r];
#pragma unroll
            for (int off = 1; off < 16; off <<= 1)
                m = fminf(m, __shfl_xor(m, off));
            if (l16 == 0) {
                int row = rowStrip + rt * 16 + quad * 4 + r;
                float val = fmaxf(m + n2[row], 0.f);
                atomicMin(&negBits[row], __float_as_uint(val));
            }
        }
    }

    // ---- last-block-done finalize: loss = mean relu(ap - an + margin) ----
    __syncthreads();
    __shared__ unsigned lastFlag;
    if (threadIdx.x == 0) {
        __threadfence();
        unsigned old = atomicAdd(cnt, 1u);
        lastFlag = (old == gridDim.x - 1) ? 1u : 0u;
    }
    __syncthreads();
    if (lastFlag) {
        float s = 0.f;
        for (int k = threadIdx.x; k < N_TOTAL; k += 256) {
            unsigned u = atomicOr(&negBits[k], 0u);  // device-coherent read
            float an = sqrtf(__uint_as_float(u));
            s += fmaxf(ap[k] - an + MARGIN, 0.f);
        }
#pragma unroll
        for (int off = 1; off < 64; off <<= 1) s += __shfl_xor(s, off);
        __shared__ float wsum[4];
        if (lane == 0) wsum[w] = s;
        __syncthreads();
        if (threadIdx.x == 0)
            out[0] = (wsum[0] + wsum[1] + wsum[2] + wsum[3]) * (1.0f / N_TOTAL);
    }
}

extern "C" void kernel_launch(void* const* d_in, const int* in_sizes, int n_in,
                              void* d_out, int out_size, void* d_ws, size_t ws_size,
                              hipStream_t stream) {
    const float* emb = (const float*)d_in[0];
    float* out = (float*)d_out;

    char* ws = (char*)d_ws;
    unsigned short* ebf     = (unsigned short*)ws;                          // 2 MiB
    float*          n2      = (float*)(ws + 2 * 1024 * 1024);               // 32 KiB
    float*          ap      = (float*)(ws + 2 * 1024 * 1024 + 32 * 1024);   // 32 KiB
    unsigned*       negBits = (unsigned*)(ws + 2 * 1024 * 1024 + 64 * 1024);// 32 KiB
    unsigned*       cnt     = (unsigned*)(ws + 2 * 1024 * 1024 + 96 * 1024);

    prep_pos_kernel<<<N_TOTAL / CSIZE / 4, 256, 0, stream>>>(emb, ebf, n2, ap, negBits, cnt);
    neg_kernel<<<(N_TOTAL / 256) * 16, 256, 0, stream>>>(ebf, n2, ap, negBits, cnt, out);
}

// Round 3
// 92.686 us; speedup vs baseline: 1.9448x; 1.2284x over previous
//
#include <hip/hip_runtime.h>
#include <stdint.h>

// Problem constants (CLUSTER_AMNT=1024, CLUSTER_SIZE=8, EMBED_DIM=128)
#define N_TOTAL 8192
#define EMBED   128
#define CSIZE   8
#define MARGIN  1.0f
#define BIGF    3.0e38f

#define SEGS         16
#define COLS_PER_SEG (N_TOTAL / SEGS)      // 512
#define STEP_COLS    32
#define STEPS        (COLS_PER_SEG / STEP_COLS)  // 16

typedef __attribute__((ext_vector_type(8))) short  short8;   // 8 bf16 (4 VGPRs)
typedef __attribute__((ext_vector_type(4))) float  floatx4;  // MFMA C/D

__device__ __forceinline__ unsigned short f2bf(float f) {
    union { float f; unsigned u; } v; v.f = f;
    unsigned u = v.u;
    unsigned r = u + 0x7FFFu + ((u >> 16) & 1u);  // RNE bf16
    return (unsigned short)(r >> 16);
}

__device__ __forceinline__ void gl_lds16(const void* g, void* l) {
    __builtin_amdgcn_global_load_lds(
        (const __attribute__((address_space(1))) void*)g,
        (__attribute__((address_space(3))) void*)l, 16, 0, 0);
}

// ---------------------------------------------------------------------------
// prep_pos: fused. 4 waves/block, one cluster per wave (wave-synchronous).
// fp32->bf16 cast-out, exact fp32 row norms, hard positive, negBits=+inf.
// ---------------------------------------------------------------------------
__global__ __launch_bounds__(256) void prep_pos_kernel(
        const float* __restrict__ emb,
        unsigned short* __restrict__ ebf,
        float* __restrict__ n2,
        float* __restrict__ ap,
        unsigned* __restrict__ negBits,
        unsigned* __restrict__ cnt) {
    __shared__ float ls[4][CSIZE][EMBED + 1];
    int tid  = threadIdx.x;
    int w    = tid >> 6;
    int lane = tid & 63;
    int c    = blockIdx.x * 4 + w;

    const float4* base = (const float4*)(emb + (size_t)c * CSIZE * EMBED);
    float4 v[4];
#pragma unroll
    for (int i = 0; i < 4; ++i) v[i] = base[lane + i * 64];

#pragma unroll
    for (int i = 0; i < 4; ++i) {
        int elem = (lane + i * 64) * 4;
        int r = elem >> 7, k = elem & 127;
        ls[w][r][k]     = v[i].x;
        ls[w][r][k + 1] = v[i].y;
        ls[w][r][k + 2] = v[i].z;
        ls[w][r][k + 3] = v[i].w;
    }

    ushort4* dst = (ushort4*)(ebf + (size_t)c * CSIZE * EMBED);
#pragma unroll
    for (int i = 0; i < 4; ++i) {
        ushort4 o;
        o.x = f2bf(v[i].x); o.y = f2bf(v[i].y);
        o.z = f2bf(v[i].z); o.w = f2bf(v[i].w);
        dst[lane + i * 64] = o;
    }

    int i8 = lane >> 3, j8 = lane & 7;
    float sq = 0.f, s2 = 0.f;
#pragma unroll 8
    for (int k = 0; k < EMBED; ++k) {
        float a = ls[w][i8][k];
        float d = a - ls[w][j8][k];
        sq = fmaf(d, d, sq);
        s2 = fmaf(a, a, s2);
    }
#pragma unroll
    for (int off = 1; off < 8; off <<= 1) sq = fmaxf(sq, __shfl_xor(sq, off));
    if (j8 == 0) {
        ap[c * CSIZE + i8] = sqrtf(sq);
        n2[c * CSIZE + i8] = s2;
    }
    if (lane < CSIZE) negBits[c * CSIZE + lane] = 0x7F800000u;  // +inf
    if (blockIdx.x == 0 && tid == 0) cnt[0] = 0u;
}

// ---------------------------------------------------------------------------
// neg: bf16 MFMA Gram, B staged through LDS (global_load_lds w=16, shared by
// all 4 waves), m97-style 2-barrier K-loop. Wave owns 64 rows (A in regs).
// acc init = -0.5*n2_col so min(n2c - 2G) == -2 * max(acc): 1 fmax/elem.
// Last block reduces the loss and writes out[0].
// ---------------------------------------------------------------------------
__global__ __launch_bounds__(256, 2) void neg_kernel(
        const unsigned short* __restrict__ ebf,
        const float* __restrict__ n2,
        const float* __restrict__ ap,
        unsigned* __restrict__ negBits,
        unsigned* __restrict__ cnt,
        float* __restrict__ out) {
    __shared__ __align__(16) unsigned char btile[STEP_COLS * 256];  // 8 KB
    int lane = threadIdx.x & 63;
    int w    = threadIdx.x >> 6;
    int quad = lane >> 4;
    int l16  = lane & 15;
    int rowBlock = blockIdx.x >> 4;          // 32 row blocks of 256 rows
    int seg      = blockIdx.x & (SEGS - 1);  // 16 segments of 512 cols
    int rowStrip = rowBlock * 256 + w * 64;
    int colBase0 = seg * COLS_PER_SEG;

    // A fragments: 4 row-tiles x 4 K-chunks, 64 VGPRs. A[m=l16][k=quad*8+j+32c]
    short8 afrag[4][4];
#pragma unroll
    for (int rt = 0; rt < 4; ++rt)
#pragma unroll
        for (int c = 0; c < 4; ++c)
            afrag[rt][c] = *(const short8*)(ebf +
                (size_t)(rowStrip + rt * 16 + l16) * EMBED + c * 32 + quad * 8);

    float mx[4][4];  // running max of (G_ij - 0.5*n2_j)
#pragma unroll
    for (int rt = 0; rt < 4; ++rt)
#pragma unroll
        for (int r = 0; r < 4; ++r) mx[rt][r] = -BIGF;

    // staging geometry (per wave: 2 insts, si = w*2+i covers cols 4si..4si+3)
    const char* gbase = (const char*)ebf;
    int jl[2], chn[2];
#pragma unroll
    for (int i = 0; i < 2; ++i) {
        int si = w * 2 + i;
        jl[i]  = 4 * si + (lane >> 4);           // 0..31 local col
        chn[i] = (lane & 15) ^ (jl[i] & 15);     // xor-swizzled 16B chunk
    }

#pragma unroll 1
    for (int t = 0; t < STEPS; ++t) {
        int colBase = colBase0 + t * STEP_COLS;
        __syncthreads();  // previous consumers done; safe to overwrite btile
#pragma unroll
        for (int i = 0; i < 2; ++i) {
            int si = w * 2 + i;
            const char* gp = gbase + ((size_t)(colBase + jl[i]) << 8) + (chn[i] << 4);
            gl_lds16(gp, (char*)btile + (si << 10));
        }
        float nhalf0 = -0.5f * n2[colBase + l16];
        float nhalf1 = -0.5f * n2[colBase + 16 + l16];
        __syncthreads();  // staging (vmcnt drain) complete -> btile valid

#pragma unroll
        for (int h = 0; h < 2; ++h) {
            float nh = h ? nhalf1 : nhalf0;
            short8 bfrag[4];
#pragma unroll
            for (int c = 0; c < 4; ++c)
                bfrag[c] = *(const short8*)(btile +
                    (((h * 16 + l16) << 8) | ((((c << 2) + quad) ^ l16) << 4)));
            int colB = colBase + h * 16;
#pragma unroll
            for (int rt = 0; rt < 4; ++rt) {
                floatx4 acc = {nh, nh, nh, nh};
#pragma unroll
                for (int c = 0; c < 4; ++c)
                    acc = __builtin_amdgcn_mfma_f32_16x16x32_bf16(
                        afrag[rt][c], bfrag[c], acc, 0, 0, 0);
                if (colB == rowStrip + rt * 16) {  // wave-uniform: diagonal tile
                    bool skip = ((quad >> 1) == (l16 >> 3));  // same 8-cluster
#pragma unroll
                    for (int r = 0; r < 4; ++r) {
                        float v = skip ? -BIGF : acc[r];
                        mx[rt][r] = fmaxf(mx[rt][r], v);
                    }
                } else {
#pragma unroll
                    for (int r = 0; r < 4; ++r)
                        mx[rt][r] = fmaxf(mx[rt][r], acc[r]);
                }
            }
        }
    }

    // reduce over the 16 columns (lanes sharing quad), commit per-row min
#pragma unroll
    for (int rt = 0; rt < 4; ++rt) {
#pragma unroll
        for (int r = 0; r < 4; ++r) {
            float m = mx[rt][r];
#pragma unroll
            for (int off = 1; off < 16; off <<= 1)
                m = fmaxf(m, __shfl_xor(m, off));
            if (l16 == 0) {
                int row = rowStrip + rt * 16 + quad * 4 + r;
                float val = fmaxf(fmaf(-2.f, m, n2[row]), 0.f);  // n2r + n2c - 2G
                atomicMin(&negBits[row], __float_as_uint(val));
            }
        }
    }

    // ---- last-block finalize: out = mean relu(ap - an + margin) ----
    __syncthreads();
    __shared__ unsigned lastFlag;
    if (threadIdx.x == 0) {
        __threadfence();
        unsigned old = atomicAdd(cnt, 1u);
        lastFlag = (old == gridDim.x - 1) ? 1u : 0u;
    }
    __syncthreads();
    if (lastFlag) {
        float s = 0.f;
#pragma unroll 4
        for (int k = threadIdx.x; k < N_TOTAL; k += 256) {
            unsigned u = atomicOr(&negBits[k], 0u);  // device-coherent read
            float an = sqrtf(__uint_as_float(u));
            s += fmaxf(ap[k] - an + MARGIN, 0.f);
        }
#pragma unroll
        for (int off = 1; off < 64; off <<= 1) s += __shfl_xor(s, off);
        __shared__ float wsum[4];
        if (lane == 0) wsum[w] = s;
        __syncthreads();
        if (threadIdx.x == 0)
            out[0] = (wsum[0] + wsum[1] + wsum[2] + wsum[3]) * (1.0f / N_TOTAL);
    }
}

extern "C" void kernel_launch(void* const* d_in, const int* in_sizes, int n_in,
                              void* d_out, int out_size, void* d_ws, size_t ws_size,
                              hipStream_t stream) {
    const float* emb = (const float*)d_in[0];
    float* out = (float*)d_out;

    char* ws = (char*)d_ws;
    unsigned short* ebf     = (unsigned short*)ws;                          // 2 MiB
    float*          n2      = (float*)(ws + 2 * 1024 * 1024);               // 32 KiB
    float*          ap      = (float*)(ws + 2 * 1024 * 1024 + 32 * 1024);   // 32 KiB
    unsigned*       negBits = (unsigned*)(ws + 2 * 1024 * 1024 + 64 * 1024);// 32 KiB
    unsigned*       cnt     = (unsigned*)(ws + 2 * 1024 * 1024 + 96 * 1024);

    prep_pos_kernel<<<N_TOTAL / CSIZE / 4, 256, 0, stream>>>(emb, ebf, n2, ap, negBits, cnt);
    neg_kernel<<<(N_TOTAL / 256) * SEGS, 256, 0, stream>>>(ebf, n2, ap, negBits, cnt, out);
}

// Round 4
// 88.749 us; speedup vs baseline: 2.0310x; 1.0444x over previous
//
#include <hip/hip_runtime.h>
#include <stdint.h>

// Problem constants (CLUSTER_AMNT=1024, CLUSTER_SIZE=8, EMBED_DIM=128)
#define N_TOTAL 8192
#define EMBED   128
#define CSIZE   8
#define MARGIN  1.0f
#define BIGF    3.0e38f

#define SEGS         16
#define COLS_PER_SEG (N_TOTAL / SEGS)            // 512
#define STEP_COLS    32
#define STEPS        (COLS_PER_SEG / STEP_COLS)  // 16
#define ROW_BLOCKS   (N_TOTAL / 256)             // 32

typedef __attribute__((ext_vector_type(8))) short  short8;   // 8 bf16 (4 VGPRs)
typedef __attribute__((ext_vector_type(4))) float  floatx4;  // MFMA C/D

__device__ __forceinline__ unsigned short f2bf(float f) {
    union { float f; unsigned u; } v; v.f = f;
    unsigned u = v.u;
    unsigned r = u + 0x7FFFu + ((u >> 16) & 1u);  // RNE bf16
    return (unsigned short)(r >> 16);
}

__device__ __forceinline__ void gl_lds16(const void* g, void* l) {
    __builtin_amdgcn_global_load_lds(
        (const __attribute__((address_space(1))) void*)g,
        (__attribute__((address_space(3))) void*)l, 16, 0, 0);
}

// ---------------------------------------------------------------------------
// prep_pos: fused. 4 waves/block, one cluster per wave (wave-synchronous).
// fp32->bf16 cast-out, exact fp32 row norms, hard positive, negBits=+inf,
// zero the 32 per-rowBlock done counters and out[0].
// ---------------------------------------------------------------------------
__global__ __launch_bounds__(256) void prep_pos_kernel(
        const float* __restrict__ emb,
        unsigned short* __restrict__ ebf,
        float* __restrict__ n2,
        float* __restrict__ ap,
        unsigned* __restrict__ negBits,
        unsigned* __restrict__ cnt,
        float* __restrict__ out) {
    __shared__ __align__(16) float ls[4][CSIZE][EMBED + 4];  // row stride 132
    int tid  = threadIdx.x;
    int w    = tid >> 6;
    int lane = tid & 63;
    int c    = blockIdx.x * 4 + w;

    const float4* base = (const float4*)(emb + (size_t)c * CSIZE * EMBED);
    float4 v[4];
#pragma unroll
    for (int i = 0; i < 4; ++i) v[i] = base[lane + i * 64];

#pragma unroll
    for (int i = 0; i < 4; ++i) {
        int elem = (lane + i * 64) * 4;
        int r = elem >> 7, k = elem & 127;
        *(float4*)&ls[w][r][k] = v[i];
    }

    ushort4* dst = (ushort4*)(ebf + (size_t)c * CSIZE * EMBED);
#pragma unroll
    for (int i = 0; i < 4; ++i) {
        ushort4 o;
        o.x = f2bf(v[i].x); o.y = f2bf(v[i].y);
        o.z = f2bf(v[i].z); o.w = f2bf(v[i].w);
        dst[lane + i * 64] = o;
    }

    int i8 = lane >> 3, j8 = lane & 7;
    float sq = 0.f, s2 = 0.f;
#pragma unroll 8
    for (int k4 = 0; k4 < EMBED / 4; ++k4) {
        float4 a = *(const float4*)&ls[w][i8][k4 * 4];
        float4 b = *(const float4*)&ls[w][j8][k4 * 4];
        float d0 = a.x - b.x, d1 = a.y - b.y, d2 = a.z - b.z, d3 = a.w - b.w;
        sq = fmaf(d0, d0, sq); sq = fmaf(d1, d1, sq);
        sq = fmaf(d2, d2, sq); sq = fmaf(d3, d3, sq);
        s2 = fmaf(a.x, a.x, s2); s2 = fmaf(a.y, a.y, s2);
        s2 = fmaf(a.z, a.z, s2); s2 = fmaf(a.w, a.w, s2);
    }
#pragma unroll
    for (int off = 1; off < 8; off <<= 1) sq = fmaxf(sq, __shfl_xor(sq, off));
    if (j8 == 0) {
        ap[c * CSIZE + i8] = sqrtf(sq);
        n2[c * CSIZE + i8] = s2;
    }
    if (lane < CSIZE) negBits[c * CSIZE + lane] = 0x7F800000u;  // +inf
    if (blockIdx.x == 0) {
        if (tid < ROW_BLOCKS) cnt[tid] = 0u;
        if (tid == 0) out[0] = 0.f;
    }
}

// ---------------------------------------------------------------------------
// neg: bf16 MFMA Gram, B staged through double-buffered LDS
// (global_load_lds w=16, shared by all 4 waves). One barrier per step:
// stage(t+1) issued BEFORE consuming tile t, so the pre-barrier vmcnt drain
// overlaps with MFMA work. acc init = -0.5*n2_col (from an LDS n2 tile) so
// min(n2c - 2G) == -2*max(acc). Per-rowBlock last-done block reduces that
// rowBlock's 256 loss terms and atomicAdds into out[0].
// ---------------------------------------------------------------------------
__global__ __launch_bounds__(256, 2) void neg_kernel(
        const unsigned short* __restrict__ ebf,
        const float* __restrict__ n2,
        const float* __restrict__ ap,
        unsigned* __restrict__ negBits,
        unsigned* __restrict__ cnt,
        float* __restrict__ out) {
    __shared__ __align__(16) unsigned char btile[2][STEP_COLS * 256];  // 2 x 8 KB
    __shared__ float n2l[COLS_PER_SEG];                                // 2 KB
    int lane = threadIdx.x & 63;
    int w    = threadIdx.x >> 6;
    int quad = lane >> 4;
    int l16  = lane & 15;
    int rowBlock = blockIdx.x >> 4;          // 32 row blocks of 256 rows
    int seg      = blockIdx.x & (SEGS - 1);  // 16 segments of 512 cols
    int rowStrip = rowBlock * 256 + w * 64;
    int colBase0 = seg * COLS_PER_SEG;

    // n2 tile for this segment (scaled): ds_read in-loop -> lgkmcnt only
    for (int k = threadIdx.x; k < COLS_PER_SEG; k += 256)
        n2l[k] = -0.5f * n2[colBase0 + k];

    // A fragments: 4 row-tiles x 4 K-chunks, 64 VGPRs. A[m=l16][k=quad*8+j+32c]
    short8 afrag[4][4];
#pragma unroll
    for (int rt = 0; rt < 4; ++rt)
#pragma unroll
        for (int c = 0; c < 4; ++c)
            afrag[rt][c] = *(const short8*)(ebf +
                (size_t)(rowStrip + rt * 16 + l16) * EMBED + c * 32 + quad * 8);

    float mx[4][4];  // running max of (G_ij - 0.5*n2_j)
#pragma unroll
    for (int rt = 0; rt < 4; ++rt)
#pragma unroll
        for (int r = 0; r < 4; ++r) mx[rt][r] = -BIGF;

    // staging geometry (per wave: 2 insts; si = w*2+i covers cols 4si..4si+3)
    const char* gbase = (const char*)ebf;
    int jl[2], chn[2];
#pragma unroll
    for (int i = 0; i < 2; ++i) {
        int si = w * 2 + i;
        jl[i]  = 4 * si + (lane >> 4);           // 0..31 local col
        chn[i] = (lane & 15) ^ (jl[i] & 15);     // xor-swizzled 16B chunk
    }

    // prime buffer 0
#pragma unroll
    for (int i = 0; i < 2; ++i) {
        int si = w * 2 + i;
        const char* gp = gbase + ((size_t)(colBase0 + jl[i]) << 8) + (chn[i] << 4);
        gl_lds16(gp, (char*)btile[0] + (si << 10));
    }
    __syncthreads();  // buffer 0 staged, n2l ready

#pragma unroll 1
    for (int t = 0; t < STEPS; ++t) {
        int cur = t & 1;
        if (t < STEPS - 1) {  // prefetch t+1 into the other buffer
#pragma unroll
            for (int i = 0; i < 2; ++i) {
                int si = w * 2 + i;
                const char* gp = gbase +
                    ((size_t)(colBase0 + (t + 1) * STEP_COLS + jl[i]) << 8) + (chn[i] << 4);
                gl_lds16(gp, (char*)btile[cur ^ 1] + (si << 10));
            }
        }
        int colBase = colBase0 + t * STEP_COLS;
        float nhalf0 = n2l[t * STEP_COLS + l16];
        float nhalf1 = n2l[t * STEP_COLS + 16 + l16];

#pragma unroll
        for (int h = 0; h < 2; ++h) {
            float nh = h ? nhalf1 : nhalf0;
            short8 bfrag[4];
#pragma unroll
            for (int c = 0; c < 4; ++c)
                bfrag[c] = *(const short8*)((const unsigned char*)btile[cur] +
                    (((h * 16 + l16) << 8) | ((((c << 2) + quad) ^ l16) << 4)));
            int colB = colBase + h * 16;
#pragma unroll
            for (int rt = 0; rt < 4; ++rt) {
                floatx4 acc = {nh, nh, nh, nh};
#pragma unroll
                for (int c = 0; c < 4; ++c)
                    acc = __builtin_amdgcn_mfma_f32_16x16x32_bf16(
                        afrag[rt][c], bfrag[c], acc, 0, 0, 0);
                if (colB == rowStrip + rt * 16) {  // wave-uniform: diagonal tile
                    bool skip = ((quad >> 1) == (l16 >> 3));  // same 8-cluster
#pragma unroll
                    for (int r = 0; r < 4; ++r) {
                        float v = skip ? -BIGF : acc[r];
                        mx[rt][r] = fmaxf(mx[rt][r], v);
                    }
                } else {
#pragma unroll
                    for (int r = 0; r < 4; ++r)
                        mx[rt][r] = fmaxf(mx[rt][r], acc[r]);
                }
            }
        }
        __syncthreads();  // readers of btile[cur] done; stage(t+1) drained
    }

    // reduce over 16 columns (lanes sharing quad), commit per-row min
#pragma unroll
    for (int rt = 0; rt < 4; ++rt) {
#pragma unroll
        for (int r = 0; r < 4; ++r) {
            float m = mx[rt][r];
#pragma unroll
            for (int off = 1; off < 16; off <<= 1)
                m = fmaxf(m, __shfl_xor(m, off));
            if (l16 == 0) {
                int row = rowStrip + rt * 16 + quad * 4 + r;
                float val = fmaxf(fmaf(-2.f, m, n2[row]), 0.f);  // n2r+n2c-2G
                atomicMin(&negBits[row], __float_as_uint(val));
            }
        }
    }

    // ---- per-rowBlock finalize: last of 16 segment blocks reduces 256 rows
    __syncthreads();
    __shared__ unsigned lastFlag;
    __shared__ float wsum[4];
    if (threadIdx.x == 0) {
        __threadfence();
        unsigned old = atomicAdd(&cnt[rowBlock], 1u);
        lastFlag = (old == SEGS - 1) ? 1u : 0u;
    }
    __syncthreads();
    if (lastFlag) {
        int row = rowBlock * 256 + threadIdx.x;
        unsigned u = atomicOr(&negBits[row], 0u);  // device-coherent read
        float an = sqrtf(__uint_as_float(u));
        float s  = fmaxf(ap[row] - an + MARGIN, 0.f);
#pragma unroll
        for (int off = 1; off < 64; off <<= 1) s += __shfl_xor(s, off);
        if (lane == 0) wsum[w] = s;
        __syncthreads();
        if (threadIdx.x == 0)
            atomicAdd(out, (wsum[0] + wsum[1] + wsum[2] + wsum[3]) * (1.0f / N_TOTAL));
    }
}

extern "C" void kernel_launch(void* const* d_in, const int* in_sizes, int n_in,
                              void* d_out, int out_size, void* d_ws, size_t ws_size,
                              hipStream_t stream) {
    const float* emb = (const float*)d_in[0];
    float* out = (float*)d_out;

    char* ws = (char*)d_ws;
    unsigned short* ebf     = (unsigned short*)ws;                          // 2 MiB
    float*          n2      = (float*)(ws + 2 * 1024 * 1024);               // 32 KiB
    float*          ap      = (float*)(ws + 2 * 1024 * 1024 + 32 * 1024);   // 32 KiB
    unsigned*       negBits = (unsigned*)(ws + 2 * 1024 * 1024 + 64 * 1024);// 32 KiB
    unsigned*       cnt     = (unsigned*)(ws + 2 * 1024 * 1024 + 96 * 1024);

    prep_pos_kernel<<<N_TOTAL / CSIZE / 4, 256, 0, stream>>>(emb, ebf, n2, ap, negBits, cnt, out);
    neg_kernel<<<(N_TOTAL / 256) * SEGS, 256, 0, stream>>>(ebf, n2, ap, negBits, cnt, out);
}